// Round 1
// baseline (129.624 us; speedup 1.0000x reference)
//
#include <hip/hip_runtime.h>
#include <hip/hip_bf16.h>

typedef __attribute__((ext_vector_type(4))) float f32x4;
typedef __attribute__((ext_vector_type(8))) short bf16x8;

#define T_DIM 8192
#define B_DIM 16
#define F_DIM 32
#define L_DIM 16
#define NTAPS 10
#define O_DIM 128
#define M_TOTAL (T_DIM * B_DIM)   // 131072 rows, row r = t*16 + b

static __device__ __forceinline__ unsigned short f2bf(float f) {
    union { float f; unsigned int u; } v; v.f = f;
    unsigned int r = v.u + 0x7fffu + ((v.u >> 16) & 1u);   // RNE
    return (unsigned short)(r >> 16);
}

// ---------------------------------------------------------------------------
// Kernel 1: fold emission+decoder into the conv kernel.
//   W2[o,s,f] = sum_l dec_w[o,l] * sum_op em_w[l,op] * K[l,s,op,f]
// Written as bf16 directly in MFMA B-fragment layout:
//   w2f[((s*8+nt)*64 + lane)*8 + j] = bf16(W2[nt*16+(lane&15)][s][(lane>>4)*8+j])
// bias2[o] = dec_b[o] + sum_l dec_w[o,l]*em_b[l]
// Grid: 80 blocks (s*8+nt) x 256 threads (4 l-groups x 64 lanes).
// ---------------------------------------------------------------------------
__global__ __launch_bounds__(256) void build_w2_kernel(
    const float* __restrict__ K, const float* __restrict__ em_w,
    const float* __restrict__ em_b, const float* __restrict__ dec_w,
    const float* __restrict__ dec_b, unsigned short* __restrict__ w2f,
    float* __restrict__ bias2)
{
    int s    = blockIdx.x >> 3;
    int nt   = blockIdx.x & 7;
    int lg   = threadIdx.x >> 6;   // l-group 0..3
    int lane = threadIdx.x & 63;
    int o     = nt * 16 + (lane & 15);
    int fbase = (lane >> 4) * 8;

    float acc[8] = {0.f,0.f,0.f,0.f,0.f,0.f,0.f,0.f};
    for (int l = lg * 4; l < lg * 4 + 4; ++l) {
        float dw = dec_w[o * L_DIM + l];
        const float* Kb = K + (size_t)(l * NTAPS + s) * F_DIM * F_DIM;
        for (int op = 0; op < F_DIM; ++op) {
            float e = em_w[l * F_DIM + op] * dw;
            const float* Kr = Kb + op * F_DIM + fbase;
            #pragma unroll
            for (int j = 0; j < 8; ++j) acc[j] += e * Kr[j];
        }
    }

    __shared__ float red[4][64][8];
    #pragma unroll
    for (int j = 0; j < 8; ++j) red[lg][lane][j] = acc[j];
    __syncthreads();

    if (lg == 0) {
        unsigned short out8[8];
        #pragma unroll
        for (int j = 0; j < 8; ++j) {
            float v = red[0][lane][j] + red[1][lane][j] +
                      red[2][lane][j] + red[3][lane][j];
            out8[j] = f2bf(v);
        }
        unsigned short* dst = w2f + ((size_t)(s * 8 + nt) * 64 + lane) * 8;
        *(bf16x8*)dst = *(const bf16x8*)out8;

        if (s == 0 && lane < 16) {
            int oo = nt * 16 + lane;
            float bsum = dec_b[oo];
            for (int l = 0; l < L_DIM; ++l) bsum += dec_w[oo * L_DIM + l] * em_b[l];
            bias2[oo] = bsum;
        }
    }
}

// ---------------------------------------------------------------------------
// Kernel 2: x (fp32, T*B x 32) -> bf16 rows (64B/row)
// ---------------------------------------------------------------------------
__global__ __launch_bounds__(256) void convert_x_kernel(
    const float* __restrict__ x, unsigned short* __restrict__ xb)
{
    size_t i = ((size_t)blockIdx.x * 256 + threadIdx.x) * 8;
    f32x4 a = *(const f32x4*)(x + i);
    f32x4 b = *(const f32x4*)(x + i + 4);
    unsigned short r[8];
    #pragma unroll
    for (int j = 0; j < 4; ++j) r[j]     = f2bf(a[j]);
    #pragma unroll
    for (int j = 0; j < 4; ++j) r[4 + j] = f2bf(b[j]);
    *(bf16x8*)(xb + i) = *(const bf16x8*)r;
}

// ---------------------------------------------------------------------------
// Kernel 3: main conv-as-shifted-GEMM.
// Each wave: 32 output rows x 128 cols. acc = 2x8 frags of 16x16.
// Tap s == x row array shifted by s*16 rows (r0 multiple of 16 -> fragment
// is uniformly in-range or fully zero-padded: uniform branch, no lane preds).
// ---------------------------------------------------------------------------
__global__ __launch_bounds__(256) void s4_main_kernel(
    const unsigned short* __restrict__ xb,
    const unsigned short* __restrict__ w2f,
    const float* __restrict__ bias2,
    float* __restrict__ out)
{
    int wave = threadIdx.x >> 6;
    int lane = threadIdx.x & 63;
    int row0 = (blockIdx.x * 4 + wave) * 32;

    f32x4 acc[2][8];
    #pragma unroll
    for (int mt = 0; mt < 2; ++mt)
        #pragma unroll
        for (int nt = 0; nt < 8; ++nt)
            acc[mt][nt] = (f32x4){0.f, 0.f, 0.f, 0.f};

    int lrow = lane & 15;         // A-row within fragment
    int fofs = (lane >> 4) * 8;   // k-offset (feature)

    for (int s = 0; s < NTAPS; ++s) {
        bf16x8 bfrag[8];
        const bf16x8* wp = (const bf16x8*)w2f + (size_t)(s * 8) * 64 + lane;
        #pragma unroll
        for (int nt = 0; nt < 8; ++nt) bfrag[nt] = wp[nt * 64];

        #pragma unroll
        for (int mt = 0; mt < 2; ++mt) {
            int r0 = row0 + mt * 16 - s * 16;
            if (r0 >= 0) {
                bf16x8 afrag = *(const bf16x8*)(xb + (size_t)(r0 + lrow) * F_DIM + fofs);
                #pragma unroll
                for (int nt = 0; nt < 8; ++nt)
                    acc[mt][nt] = __builtin_amdgcn_mfma_f32_16x16x32_bf16(
                        afrag, bfrag[nt], acc[mt][nt], 0, 0, 0);
            }
        }
    }

    // Epilogue: C frag mapping col=lane&15, row=(lane>>4)*4+j  (m89-verified)
    int og = lane & 15;
    int rg = (lane >> 4) * 4;
    #pragma unroll
    for (int mt = 0; mt < 2; ++mt) {
        #pragma unroll
        for (int nt = 0; nt < 8; ++nt) {
            int o = nt * 16 + og;
            float bo = bias2[o];
            #pragma unroll
            for (int j = 0; j < 4; ++j) {
                int r = row0 + mt * 16 + rg + j;
                int t = r >> 4;
                int b = r & 15;
                out[((size_t)b * T_DIM + t) * O_DIM + o] = acc[mt][nt][j] + bo;
            }
        }
    }
}

extern "C" void kernel_launch(void* const* d_in, const int* in_sizes, int n_in,
                              void* d_out, int out_size, void* d_ws, size_t ws_size,
                              hipStream_t stream)
{
    const float* x     = (const float*)d_in[0];
    const float* K     = (const float*)d_in[1];
    const float* em_w  = (const float*)d_in[2];
    const float* em_b  = (const float*)d_in[3];
    const float* dec_w = (const float*)d_in[4];
    const float* dec_b = (const float*)d_in[5];
    float* out = (float*)d_out;

    const size_t xb_bytes  = (size_t)M_TOTAL * F_DIM * 2;          // 8,388,608
    const size_t w2f_bytes = (size_t)NTAPS * 8 * 64 * 8 * 2;       // 81,920
    unsigned short* xb  = (unsigned short*)d_ws;
    unsigned short* w2f = (unsigned short*)((char*)d_ws + xb_bytes);
    float* bias2 = (float*)((char*)d_ws + xb_bytes + w2f_bytes);

    hipLaunchKernelGGL(build_w2_kernel, dim3(80), dim3(256), 0, stream,
                       K, em_w, em_b, dec_w, dec_b, w2f, bias2);
    hipLaunchKernelGGL(convert_x_kernel, dim3(M_TOTAL * F_DIM / (256 * 8)), dim3(256), 0, stream,
                       x, xb);
    hipLaunchKernelGGL(s4_main_kernel, dim3(M_TOTAL / 128), dim3(256), 0, stream,
                       xb, w2f, bias2, out);
}

// Round 2
// 122.275 us; speedup vs baseline: 1.0601x; 1.0601x over previous
//
#include <hip/hip_runtime.h>
#include <hip/hip_bf16.h>

typedef __attribute__((ext_vector_type(4))) float f32x4;
typedef __attribute__((ext_vector_type(8))) short bf16x8;

#define T_DIM 8192
#define B_DIM 16
#define F_DIM 32
#define L_DIM 16
#define NTAPS 10
#define O_DIM 128
#define M_TOTAL (T_DIM * B_DIM)     // 131072 output rows, row r = b*8192 + t
#define PADT (T_DIM + 16)           // 16 zero rows in front of each b-block

static __device__ __forceinline__ unsigned short f2bf(float f) {
    union { float f; unsigned int u; } v; v.f = f;
    unsigned int r = v.u + 0x7fffu + ((v.u >> 16) & 1u);   // RNE
    return (unsigned short)(r >> 16);
}

// ---------------------------------------------------------------------------
// Kernel 1: fold emission+decoder into the conv kernel, one block per tap s.
//   G[l,f]   = sum_op em_w[l,op] * K[l,s,op,f]        (LDS-staged K)
//   W2[o,s,f] = sum_l dec_w[o,l] * G[l,f]
// w2f written in MFMA fragment layout (works as A operand):
//   w2f[((s*8+nt)*64 + lane)*8 + j] = bf16(W2[nt*16+(lane&15)][s][(lane>>4)*8+j])
// bias2[o] = dec_b[o] + sum_l dec_w[o,l]*em_b[l]      (block s==0)
// ---------------------------------------------------------------------------
__global__ __launch_bounds__(256) void build_w2_kernel(
    const float* __restrict__ K, const float* __restrict__ em_w,
    const float* __restrict__ em_b, const float* __restrict__ dec_w,
    const float* __restrict__ dec_b, unsigned short* __restrict__ w2f,
    float* __restrict__ bias2)
{
    int s = blockIdx.x;
    int tid = threadIdx.x;

    __shared__ float Klds[16 * 1024];   // K[l, s, op, f] for all l   (64 KB)
    __shared__ float Glds[16 * 32];     // G[l, f]                    (2 KB)

    // coalesced load of K[l, s, :, :] for all 16 l (4 KB each)
    #pragma unroll
    for (int l = 0; l < 16; ++l) {
        const float* src = K + (size_t)(l * NTAPS + s) * 1024 + tid * 4;
        *(f32x4*)(Klds + l * 1024 + tid * 4) = *(const f32x4*)src;
    }
    __syncthreads();

    // G[l][f], 512 outputs, 2 per thread
    #pragma unroll
    for (int rep = 0; rep < 2; ++rep) {
        int idx = rep * 256 + tid;
        int l = idx >> 5, f = idx & 31;
        const float* em = em_w + l * 32;
        const float* kb = Klds + l * 1024 + f;
        float g = 0.f;
        #pragma unroll
        for (int op = 0; op < 32; ++op) g += em[op] * kb[op * 32];
        Glds[idx] = g;
    }
    __syncthreads();

    int lane = tid & 63;
    int w    = tid >> 6;
    int lo   = lane & 15;
    int fb   = (lane >> 4) * 8;
    #pragma unroll
    for (int h = 0; h < 2; ++h) {
        int nt = w + h * 4;
        int o  = nt * 16 + lo;
        float acc[8] = {0.f,0.f,0.f,0.f,0.f,0.f,0.f,0.f};
        for (int l = 0; l < 16; ++l) {
            float dw = dec_w[o * L_DIM + l];
            const float* g = Glds + l * 32 + fb;
            #pragma unroll
            for (int j = 0; j < 8; ++j) acc[j] += dw * g[j];
        }
        unsigned short o8[8];
        #pragma unroll
        for (int j = 0; j < 8; ++j) o8[j] = f2bf(acc[j]);
        *(bf16x8*)(w2f + ((size_t)(s * 8 + nt) * 64 + lane) * 8) = *(const bf16x8*)o8;
    }

    if (s == 0 && tid < O_DIM) {
        float bsum = dec_b[tid];
        #pragma unroll
        for (int l = 0; l < 16; ++l) bsum += dec_w[tid * L_DIM + l] * em_b[l];
        bias2[tid] = bsum;
    }
}

// ---------------------------------------------------------------------------
// Kernel 2: transpose-convert x (T,B,F fp32) -> xb (B, 16+T, F bf16),
// 16 explicit zero rows in front of each b-block (ws is 0xAA-poisoned!).
// Thread = one t row (64 B write, coalesced along t).
// ---------------------------------------------------------------------------
__global__ __launch_bounds__(256) void convert_x_kernel(
    const float* __restrict__ x, unsigned short* __restrict__ xb)
{
    int b = blockIdx.y;
    int t = blockIdx.x * 256 + threadIdx.x;
    const float* src = x + ((size_t)t * B_DIM + b) * F_DIM;
    unsigned short* dst = xb + ((size_t)b * PADT + 16 + t) * F_DIM;
    #pragma unroll
    for (int c = 0; c < 4; ++c) {
        f32x4 a  = *(const f32x4*)(src + c * 8);
        f32x4 bb = *(const f32x4*)(src + c * 8 + 4);
        unsigned short r[8];
        #pragma unroll
        for (int j = 0; j < 4; ++j) { r[j] = f2bf(a[j]); r[4 + j] = f2bf(bb[j]); }
        *(bf16x8*)(dst + c * 8) = *(const bf16x8*)r;
    }
    if (blockIdx.x == 0 && threadIdx.x < 16) {
        unsigned short* pz = xb + ((size_t)b * PADT + threadIdx.x) * F_DIM;
        bf16x8 z = {0,0,0,0,0,0,0,0};
        #pragma unroll
        for (int c = 0; c < 4; ++c) *(bf16x8*)(pz + c * 8) = z;
    }
}

// ---------------------------------------------------------------------------
// Kernel 3: main conv-as-shifted-GEMM, operands SWAPPED (W2 as A, x as B)
// so C-frag row index = o -> f32x4 vectorized contiguous stores.
// Wave: 32 output rows x 128 cols; tap s = x row window shifted by -s
// (always in-bounds thanks to the 16-row zero pad; causality via zeros).
// ---------------------------------------------------------------------------
__global__ __launch_bounds__(256) void s4_main_kernel(
    const unsigned short* __restrict__ xb,
    const unsigned short* __restrict__ w2f,
    const float* __restrict__ bias2,
    float* __restrict__ out)
{
    int wave = threadIdx.x >> 6;
    int lane = threadIdx.x & 63;
    int R  = (blockIdx.x * 4 + wave) * 32;   // global out-row base, r = b*8192+t
    int b  = R >> 13;
    int t0 = R & (T_DIM - 1);
    size_t xrow = (size_t)b * PADT + 16 + t0;

    int lo = lane & 15;
    int fb = (lane >> 4) * 8;

    f32x4 acc[2][8];
    #pragma unroll
    for (int mt = 0; mt < 2; ++mt)
        #pragma unroll
        for (int nt = 0; nt < 8; ++nt)
            acc[mt][nt] = (f32x4){0.f, 0.f, 0.f, 0.f};

    for (int s = 0; s < NTAPS; ++s) {
        bf16x8 wfrag[8];
        const bf16x8* wp = (const bf16x8*)w2f + (size_t)s * 8 * 64 + lane;
        #pragma unroll
        for (int nt = 0; nt < 8; ++nt) wfrag[nt] = wp[nt * 64];

        #pragma unroll
        for (int mt = 0; mt < 2; ++mt) {
            bf16x8 xfrag = *(const bf16x8*)(xb + (xrow + mt * 16 + lo - s) * F_DIM + fb);
            #pragma unroll
            for (int nt = 0; nt < 8; ++nt)
                acc[mt][nt] = __builtin_amdgcn_mfma_f32_16x16x32_bf16(
                    wfrag[nt], xfrag, acc[mt][nt], 0, 0, 0);
        }
    }

    // C mapping (swapped): col=lane&15 = out-row-within-frag, row=(lane>>4)*4+j = o
    int q = lane >> 4;
    #pragma unroll
    for (int nt = 0; nt < 8; ++nt) {
        f32x4 bi = *(const f32x4*)(bias2 + nt * 16 + q * 4);
        #pragma unroll
        for (int mt = 0; mt < 2; ++mt) {
            size_t r = (size_t)R + mt * 16 + lo;
            f32x4 v = acc[mt][nt] + bi;
            *(f32x4*)(out + r * O_DIM + nt * 16 + q * 4) = v;
        }
    }
}

extern "C" void kernel_launch(void* const* d_in, const int* in_sizes, int n_in,
                              void* d_out, int out_size, void* d_ws, size_t ws_size,
                              hipStream_t stream)
{
    const float* x     = (const float*)d_in[0];
    const float* K     = (const float*)d_in[1];
    const float* em_w  = (const float*)d_in[2];
    const float* em_b  = (const float*)d_in[3];
    const float* dec_w = (const float*)d_in[4];
    const float* dec_b = (const float*)d_in[5];
    float* out = (float*)d_out;

    const size_t xb_bytes  = (size_t)B_DIM * PADT * F_DIM * 2;   // 8,404,992
    const size_t w2f_bytes = (size_t)NTAPS * 8 * 64 * 8 * 2;     // 81,920
    unsigned short* xb  = (unsigned short*)d_ws;
    unsigned short* w2f = (unsigned short*)((char*)d_ws + xb_bytes);
    float* bias2 = (float*)((char*)d_ws + xb_bytes + w2f_bytes);

    hipLaunchKernelGGL(build_w2_kernel, dim3(NTAPS), dim3(256), 0, stream,
                       K, em_w, em_b, dec_w, dec_b, w2f, bias2);
    hipLaunchKernelGGL(convert_x_kernel, dim3(T_DIM / 256, B_DIM), dim3(256), 0, stream,
                       x, xb);
    hipLaunchKernelGGL(s4_main_kernel, dim3(M_TOTAL / 128), dim3(256), 0, stream,
                       xb, w2f, bias2, out);
}

// Round 6
// 110.008 us; speedup vs baseline: 1.1783x; 1.1115x over previous
//
#include <hip/hip_runtime.h>
#include <hip/hip_bf16.h>

typedef __attribute__((ext_vector_type(4))) float f32x4;
typedef __attribute__((ext_vector_type(8))) short bf16x8;
typedef __attribute__((ext_vector_type(4))) short bf16x4;   // 8 B

#define T_DIM 8192
#define B_DIM 16
#define F_DIM 32
#define L_DIM 16
#define NTAPS 10
#define O_DIM 128
#define M_TOTAL (T_DIM * B_DIM)

// workspace offsets (bytes)
#define G_OFF    0        // G[s][l][f] fp32: 10*16*32*4 = 20480
#define W2F_OFF  20480    // w2f frag-layout bf16: 10*8*64*8*2 = 81920
#define BIAS_OFF 102400   // bias2 fp32: 512

static __device__ __forceinline__ unsigned short f2bf(float f) {
    union { float f; unsigned int u; } v; v.f = f;
    unsigned int r = v.u + 0x7fffu + ((v.u >> 16) & 1u);   // RNE
    return (unsigned short)(r >> 16);
}

// ---------------------------------------------------------------------------
// Kernel A: G[s,l,f] = sum_op em_w[l,op] * K[l,s,op,f].  One block per (s,l).
// ---------------------------------------------------------------------------
__global__ __launch_bounds__(256) void g_stage_kernel(
    const float* __restrict__ K, const float* __restrict__ em_w,
    float* __restrict__ G)
{
    int s = blockIdx.x >> 4, l = blockIdx.x & 15;
    int f = threadIdx.x & 31, opg = threadIdx.x >> 5;   // 8 op-groups x 4
    const float* Kb = K + (size_t)(l * NTAPS + s) * 1024;
    float p = 0.f;
    #pragma unroll
    for (int k = 0; k < 4; ++k) {
        int op = opg * 4 + k;
        p += em_w[l * 32 + op] * Kb[op * 32 + f];
    }
    __shared__ float red[8][32];
    red[opg][f] = p;
    __syncthreads();
    if (threadIdx.x < 32) {
        float g = 0.f;
        #pragma unroll
        for (int q = 0; q < 8; ++q) g += red[q][threadIdx.x];
        G[(s * 16 + l) * 32 + threadIdx.x] = g;
    }
}

// ---------------------------------------------------------------------------
// Kernel B: W2[o,s,f] = sum_l dec_w[o,l] * G[s,l,f], written as bf16 MFMA
// fragments: w2f[((s*8+nt)*64+lane)*8+j] = bf16(W2[nt*16+(lane&15)][s][(lane>>4)*8+j])
// One block per (s,nt); 4 waves split l; LDS reduce. bias2 in block (0,0).
// ---------------------------------------------------------------------------
__global__ __launch_bounds__(256) void build_w2_kernel(
    const float* __restrict__ G, const float* __restrict__ em_b,
    const float* __restrict__ dec_w, const float* __restrict__ dec_b,
    unsigned short* __restrict__ w2f, float* __restrict__ bias2)
{
    int s = blockIdx.x >> 3, nt = blockIdx.x & 7;
    int lane = threadIdx.x & 63, w = threadIdx.x >> 6;
    int lo = lane & 15, fb = (lane >> 4) * 8;
    int o = nt * 16 + lo;

    float acc[8] = {0.f,0.f,0.f,0.f,0.f,0.f,0.f,0.f};
    #pragma unroll
    for (int l = 0; l < 4; ++l) {
        int ll = w * 4 + l;
        float dw = dec_w[o * L_DIM + ll];
        const float* g = G + (s * 16 + ll) * 32 + fb;
        #pragma unroll
        for (int j = 0; j < 8; ++j) acc[j] += dw * g[j];
    }
    __shared__ float red[4][64][8];
    #pragma unroll
    for (int j = 0; j < 8; ++j) red[w][lane][j] = acc[j];
    __syncthreads();
    if (w == 0) {
        unsigned short o8[8];
        #pragma unroll
        for (int j = 0; j < 8; ++j)
            o8[j] = f2bf(red[0][lane][j] + red[1][lane][j] +
                         red[2][lane][j] + red[3][lane][j]);
        *(bf16x8*)(w2f + ((size_t)(s * 8 + nt) * 64 + lane) * 8) = *(const bf16x8*)o8;
    }
    if (s == 0 && nt == 0 && threadIdx.x < O_DIM) {
        float b = dec_b[threadIdx.x];
        #pragma unroll
        for (int l = 0; l < 16; ++l) b += dec_w[threadIdx.x * L_DIM + l] * em_b[l];
        bias2[threadIdx.x] = b;
    }
}

// ---------------------------------------------------------------------------
// Kernel C: fused convert + conv-as-shifted-GEMM. 512 blocks x 512 threads,
// one 256-row tile per block. STATIC LDS only (21,760 B): x-tile of 272 rows
// x 80 B (fp32->bf16 inline, 16 zeroed front rows = causality). w2f frags
// stream from global (80 KB table, L2/L1-resident). Operands swapped
// (W2 = A) so C-frag rows = o -> contiguous f32x4 stores.
// ---------------------------------------------------------------------------
#define XROWS 272
#define XSTRIDE 80                       // bytes; stride 20 banks -> ~2-way

__global__ __launch_bounds__(512) void s4_main_kernel(
    const float* __restrict__ x, const unsigned short* __restrict__ w2f,
    const float* __restrict__ bias2, float* __restrict__ out)
{
    __shared__ char xlds[XROWS * XSTRIDE];

    int tid  = threadIdx.x;
    int lane = tid & 63, w = tid >> 6;
    int lo = lane & 15, g = lane >> 4;

    int Rb = blockIdx.x * 256;           // first out-row (r = b*8192 + t)
    int b  = Rb >> 13;
    int t0 = Rb & (T_DIM - 1);

    // stage x rows t0-16 .. t0+255 -> xlds rows 0..271, bf16, zero t<0
    #pragma unroll
    for (int rep = 0; rep < 5; ++rep) {
        int c = rep * 512 + tid;                 // 16B-fp32 chunk index
        if (c < XROWS * 8) {
            int i = c >> 3, part = c & 7;
            int t = t0 + i - 16;
            unsigned short r4[4] = {0, 0, 0, 0};
            if (t >= 0) {
                f32x4 v = *(const f32x4*)(x + ((size_t)t * B_DIM + b) * F_DIM + part * 4);
                #pragma unroll
                for (int j = 0; j < 4; ++j) r4[j] = f2bf(v[j]);
            }
            *(bf16x4*)(xlds + i * XSTRIDE + part * 8) = *(const bf16x4*)r4;
        }
    }

    f32x4 bias[8];
    #pragma unroll
    for (int nt = 0; nt < 8; ++nt)
        bias[nt] = *(const f32x4*)(bias2 + nt * 16 + g * 4);

    __syncthreads();

    f32x4 acc[2][8];
    #pragma unroll
    for (int mt = 0; mt < 2; ++mt)
        #pragma unroll
        for (int nt = 0; nt < 8; ++nt)
            acc[mt][nt] = (f32x4){0.f, 0.f, 0.f, 0.f};

    int ib = 16 + w * 32 + lo;   // xlds row for (mt=0, s=0)
    for (int s = 0; s < NTAPS; ++s) {
        bf16x8 wf[8];
        const bf16x8* wp = (const bf16x8*)w2f + (size_t)s * 8 * 64 + lane;
        #pragma unroll
        for (int nt = 0; nt < 8; ++nt) wf[nt] = wp[nt * 64];
        #pragma unroll
        for (int mt = 0; mt < 2; ++mt) {
            bf16x8 xf = *(const bf16x8*)(xlds + (ib + mt * 16 - s) * XSTRIDE + g * 16);
            #pragma unroll
            for (int nt = 0; nt < 8; ++nt)
                acc[mt][nt] = __builtin_amdgcn_mfma_f32_16x16x32_bf16(
                    wf[nt], xf, acc[mt][nt], 0, 0, 0);
        }
    }

    // epilogue: C-frag (swapped) col=lane&15=row-in-tile, row=(lane>>4)*4+j=o
    #pragma unroll
    for (int nt = 0; nt < 8; ++nt) {
        #pragma unroll
        for (int mt = 0; mt < 2; ++mt) {
            size_t r = (size_t)Rb + w * 32 + mt * 16 + lo;
            f32x4 v = acc[mt][nt] + bias[nt];
            *(f32x4*)(out + r * O_DIM + nt * 16 + g * 4) = v;
        }
    }
}

extern "C" void kernel_launch(void* const* d_in, const int* in_sizes, int n_in,
                              void* d_out, int out_size, void* d_ws, size_t ws_size,
                              hipStream_t stream)
{
    const float* x     = (const float*)d_in[0];
    const float* K     = (const float*)d_in[1];
    const float* em_w  = (const float*)d_in[2];
    const float* em_b  = (const float*)d_in[3];
    const float* dec_w = (const float*)d_in[4];
    const float* dec_b = (const float*)d_in[5];
    float* out = (float*)d_out;

    float*          Gbuf  = (float*)((char*)d_ws + G_OFF);
    unsigned short* w2f   = (unsigned short*)((char*)d_ws + W2F_OFF);
    float*          bias2 = (float*)((char*)d_ws + BIAS_OFF);

    hipLaunchKernelGGL(g_stage_kernel, dim3(NTAPS * 16), dim3(256), 0, stream,
                       K, em_w, Gbuf);
    hipLaunchKernelGGL(build_w2_kernel, dim3(NTAPS * 8), dim3(256), 0, stream,
                       Gbuf, em_b, dec_w, dec_b, w2f, bias2);
    hipLaunchKernelGGL(s4_main_kernel, dim3(M_TOTAL / 256), dim3(512), 0, stream,
                       x, w2f, bias2, out);
}